// Round 1
// baseline (380.088 us; speedup 1.0000x reference)
//
#include <hip/hip_runtime.h>
#include <math.h>

// SpectralLinear: out = x @ (M_U * diag(sigma) * M_V) + bias
// M_U = H(u0)H(u1)...H(u63), M_V = H(v63)...H(v0), H(u) = I - (2/u.u) u u^T
// Built via compact WY: H1..Hk = I - U T U^T (T upper triangular, larft).
//
// W = S - SV*R - A*F
//   A  = Umat * T_U              (512x64)
//   R  = T_V * Vmat^T            (64x512)
//   C  = (Umat^T S) Vmat         (64x64)
//   F  = (Umat^T S) - C*R        (64x512)
//   SV = S * Vmat                (folded into k_W)

#define INSIZE 512
#define NREF 64
#define BATCH 8192

// workspace layout (floats)
static constexpr int OFF_SIGMA = 0;        // 512
static constexpr int OFF_BETAU = 512;      // 64
static constexpr int OFF_BETAV = 576;      // 64
static constexpr int OFF_UMAT  = 640;      // 512*64
static constexpr int OFF_VMAT  = OFF_UMAT + 512*64;
static constexpr int OFF_GU    = OFF_VMAT + 512*64;   // 64*64
static constexpr int OFF_GV    = OFF_GU + 64*64;
static constexpr int OFF_TU    = OFF_GV + 64*64;
static constexpr int OFF_TV    = OFF_TU + 64*64;
static constexpr int OFF_A     = OFF_TV + 64*64;      // 512*64
static constexpr int OFF_R     = OFF_A + 512*64;      // 64*512
static constexpr int OFF_C     = OFF_R + 64*512;      // 64*64
static constexpr int OFF_F     = OFF_C + 64*64;       // 64*512
static constexpr int OFF_W     = OFF_F + 64*512;      // 512*512

// ---------------------------------------------------------------------------
// pack reflectors (zero leading entries), compute beta = 2/(u.u), and sigma
__global__ void k_pack(const float* __restrict__ U, const float* __restrict__ V,
                       const float* __restrict__ p, float* __restrict__ ws) {
    int b = blockIdx.x;
    int t = threadIdx.x;
    float* sigma = ws + OFF_SIGMA;
    if (b == 128) {
        for (int c = t; c < INSIZE; c += 256) {
            float pv = p[c];
            float s = 1.0f / (1.0f + expf(-pv));
            sigma[c] = 0.55f + 0.9f * (s - 0.5f);   // SIGMA_MIN=0.1, MAX=1.0
        }
        return;
    }
    bool isV = (b >= 64);
    int i = isV ? (b - 64) : b;      // packed column index (scan order)
    int row = isV ? (63 - i) : i;    // source row: V scan is reversed
    const float* src = isV ? V : U;
    float* dst = ws + (isV ? OFF_VMAT : OFF_UMAT);
    float partial = 0.f;
    for (int r = t; r < INSIZE; r += 256) {
        float v = (r >= row) ? src[row * INSIZE + r] : 0.0f;  // triu: zero j<row
        dst[r * NREF + i] = v;
        partial += v * v;
    }
    __shared__ float red[256];
    red[t] = partial;
    __syncthreads();
    for (int s = 128; s > 0; s >>= 1) {
        if (t < s) red[t] += red[t + s];
        __syncthreads();
    }
    if (t == 0) {
        float beta = 2.0f / red[0];
        (ws + (isV ? OFF_BETAV : OFF_BETAU))[i] = beta;
    }
}

// ---------------------------------------------------------------------------
// Gram matrices G[i][j] = col_i . col_j  (one wave per entry)
__global__ void k_gram(float* __restrict__ ws) {
    int bid = blockIdx.x;            // 0..8191
    int z = bid >> 12;               // 0=U, 1=V
    int rem = bid & 4095;
    int i = rem >> 6, j = rem & 63;
    const float* M = ws + (z ? OFF_VMAT : OFF_UMAT);
    float* G = ws + (z ? OFF_GV : OFF_GU);
    int t = threadIdx.x;             // 64 threads
    float s = 0.f;
    for (int r = t; r < INSIZE; r += 64)
        s += M[r * NREF + i] * M[r * NREF + j];
    for (int o = 32; o > 0; o >>= 1) s += __shfl_down(s, o, 64);
    if (t == 0) G[i * 64 + j] = s;
}

// ---------------------------------------------------------------------------
// T factor (larft forward columnwise): T(i,j) = -beta_j * sum_m T(i,m) G(m,j)
// Row i of T only depends on row i -> no cross-thread hazard.
__global__ void k_buildT(float* __restrict__ ws) {
    int z = blockIdx.x;
    const float* G = ws + (z ? OFF_GV : OFF_GU);
    const float* beta = ws + (z ? OFF_BETAV : OFF_BETAU);
    float* T = ws + (z ? OFF_TV : OFF_TU);
    int t = threadIdx.x;             // 64
    __shared__ float Tl[64][64];
    for (int j = 0; j < 64; ++j) Tl[t][j] = 0.f;
    __syncthreads();
    for (int j = 0; j < 64; ++j) {
        float bj = beta[j];
        if (t < j) {
            float s = 0.f;
            for (int m = t; m < j; ++m) s += Tl[t][m] * G[m * 64 + j];
            Tl[t][j] = -bj * s;
        } else if (t == j) {
            Tl[j][j] = bj;
        }
        __syncthreads();
    }
    for (int j = 0; j < 64; ++j) T[t * 64 + j] = Tl[t][j];
}

// ---------------------------------------------------------------------------
// A = Umat*T_U (512x64) | R = T_V*Vmat^T (64x512) | C = (U^T S)V (64x64)
__global__ void k_smallmats(float* __restrict__ ws) {
    int b = blockIdx.x, t = threadIdx.x;
    const float* Umat = ws + OFF_UMAT;
    const float* Vmat = ws + OFF_VMAT;
    const float* TU = ws + OFF_TU;
    const float* TV = ws + OFF_TV;
    const float* sigma = ws + OFF_SIGMA;
    if (b < 128) {                              // A[r,i] = sum_{m<=i} U[r,m] TU[m,i]
        int idx = b * 256 + t;
        int r = idx >> 6, i = idx & 63;
        float s = 0.f;
        for (int m = 0; m <= i; ++m) s += Umat[r * NREF + m] * TU[m * 64 + i];
        (ws + OFF_A)[r * NREF + i] = s;
    } else if (b < 256) {                       // R[i,c] = sum_{m>=i} TV[i,m] V[c,m]
        int idx = (b - 128) * 256 + t;
        int i = idx >> 9, c = idx & 511;
        float s = 0.f;
        for (int m = i; m < 64; ++m) s += TV[i * 64 + m] * Vmat[c * NREF + m];
        (ws + OFF_R)[i * INSIZE + c] = s;
    } else {                                    // C[i,j] = sum_c U[c,i] sig[c] V[c,j]
        int idx = (b - 256) * 256 + t;
        int i = idx >> 6, j = idx & 63;
        float s = 0.f;
        for (int c = 0; c < INSIZE; ++c)
            s += Umat[c * NREF + i] * sigma[c] * Vmat[c * NREF + j];
        (ws + OFF_C)[i * 64 + j] = s;
    }
}

// ---------------------------------------------------------------------------
// F[i,c] = U[c,i]*sig[c] - sum_m C[i,m] R[m,c]
__global__ void k_F(float* __restrict__ ws) {
    int idx = blockIdx.x * 256 + threadIdx.x;
    int i = idx >> 9, c = idx & 511;
    const float* C = ws + OFF_C;
    const float* R = ws + OFF_R;
    float s = (ws + OFF_UMAT)[c * NREF + i] * (ws + OFF_SIGMA)[c];
    float acc = 0.f;
    for (int m = 0; m < 64; ++m) acc += C[i * 64 + m] * R[m * INSIZE + c];
    (ws + OFF_F)[i * INSIZE + c] = s - acc;
}

// ---------------------------------------------------------------------------
// W[r,c] = sig_r*(r==c) - sum_i A[r,i]F[i,c] - sig_r * sum_i V[r,i]R[i,c]
__global__ void k_W(float* __restrict__ ws) {
    int idx = blockIdx.x * 256 + threadIdx.x;
    int r = idx >> 9, c = idx & 511;
    const float* A = ws + OFF_A;
    const float* F = ws + OFF_F;
    const float* Vm = ws + OFF_VMAT;
    const float* R = ws + OFF_R;
    float sig = (ws + OFF_SIGMA)[r];
    float acc1 = 0.f, acc2 = 0.f;
    for (int i = 0; i < 64; ++i) {
        acc1 += A[r * NREF + i] * F[i * INSIZE + c];
        acc2 += Vm[r * NREF + i] * R[i * INSIZE + c];
    }
    float w = -acc1 - sig * acc2;
    if (r == c) w += sig;
    (ws + OFF_W)[r * INSIZE + c] = w;
}

// ---------------------------------------------------------------------------
// out = x @ W + bias  : 8192x512x512 fp32, 64x64 tiles, 4x4 per thread
#define BM 64
#define BN 64
#define BK 16

__global__ __launch_bounds__(256) void k_gemm(const float* __restrict__ X,
                                              const float* __restrict__ W,
                                              const float* __restrict__ bias,
                                              float* __restrict__ out) {
    __shared__ float As[BK][BM + 1];
    __shared__ float Bs[BK][BN + 1];
    int t = threadIdx.x;
    int bm = blockIdx.y;             // 0..127
    int bn = blockIdx.x;             // 0..7
    int row0 = bm * BM, col0 = bn * BN;
    int tx = t & 15, ty = t >> 4;
    float acc[4][4] = {};
    int a_r = t >> 2;                // 0..63
    int a_k = (t & 3) * 4;           // 0,4,8,12
    int b_k = t >> 4;                // 0..15
    int b_n = (t & 15) * 4;
    for (int k0 = 0; k0 < INSIZE; k0 += BK) {
        float4 av = *(const float4*)&X[(row0 + a_r) * INSIZE + k0 + a_k];
        As[a_k + 0][a_r] = av.x;
        As[a_k + 1][a_r] = av.y;
        As[a_k + 2][a_r] = av.z;
        As[a_k + 3][a_r] = av.w;
        float4 bv = *(const float4*)&W[(k0 + b_k) * INSIZE + col0 + b_n];
        Bs[b_k][b_n + 0] = bv.x;
        Bs[b_k][b_n + 1] = bv.y;
        Bs[b_k][b_n + 2] = bv.z;
        Bs[b_k][b_n + 3] = bv.w;
        __syncthreads();
#pragma unroll
        for (int kk = 0; kk < BK; ++kk) {
            float a[4], b[4];
#pragma unroll
            for (int i = 0; i < 4; ++i) a[i] = As[kk][ty * 4 + i];
#pragma unroll
            for (int j = 0; j < 4; ++j) b[j] = Bs[kk][tx * 4 + j];
#pragma unroll
            for (int i = 0; i < 4; ++i)
#pragma unroll
                for (int j = 0; j < 4; ++j) acc[i][j] += a[i] * b[j];
        }
        __syncthreads();
    }
#pragma unroll
    for (int i = 0; i < 4; ++i) {
        int r = row0 + ty * 4 + i;
#pragma unroll
        for (int j = 0; j < 4; ++j) {
            int c = col0 + tx * 4 + j;
            out[r * INSIZE + c] = acc[i][j] + bias[c];
        }
    }
}

// ---------------------------------------------------------------------------
extern "C" void kernel_launch(void* const* d_in, const int* in_sizes, int n_in,
                              void* d_out, int out_size, void* d_ws, size_t ws_size,
                              hipStream_t stream) {
    const float* x    = (const float*)d_in[0];
    const float* p    = (const float*)d_in[1];
    const float* U    = (const float*)d_in[2];
    const float* V    = (const float*)d_in[3];
    const float* bias = (const float*)d_in[4];
    float* ws  = (float*)d_ws;
    float* out = (float*)d_out;

    k_pack<<<129, 256, 0, stream>>>(U, V, p, ws);
    k_gram<<<8192, 64, 0, stream>>>(ws);
    k_buildT<<<2, 64, 0, stream>>>(ws);
    k_smallmats<<<272, 256, 0, stream>>>(ws);
    k_F<<<128, 256, 0, stream>>>(ws);
    k_W<<<1024, 256, 0, stream>>>(ws);
    k_gemm<<<dim3(8, 128), 256, 0, stream>>>(x, ws + OFF_W, bias, out);
}

// Round 2
// 168.318 us; speedup vs baseline: 2.2582x; 2.2582x over previous
//
#include <hip/hip_runtime.h>
#include <hip/hip_bf16.h>
#include <math.h>

// SpectralLinear: out = x @ (M_U * diag(sigma) * M_V) + bias
// M_U = H(u0)...H(u63), M_V = H(v63)...H(v0), H(u) = I - (2/u.u) u u^T
// Compact WY without explicit T:  T^{-1} = strict_upper(G) + diag(1/beta)
//   A = Umat*T_U  via forward substitution  A(:,j) = b_j (U(:,j) - sum_{m<j} A(:,m) G(m,j))
//   R = T_V*V^T   via backward substitution R(i,:) = b_i (V(:,i)^T - sum_{m>i} G(i,m) R(m,:))
//   C = (U^T S) V ;  F = (U^T S) - C*R ;  W = S - SV*R - A*F
// out = x @ W + bias via bf16 MFMA (W rounded to bf16 once; fp32 accumulate).

#define INSIZE 512
#define NREF 64
#define BATCH 8192

// workspace layout (floats)
static constexpr int OFF_SIGMA = 0;        // 512
static constexpr int OFF_BETAU = 512;      // 64
static constexpr int OFF_BETAV = 576;      // 64
static constexpr int OFF_UMAT  = 640;      // 512*64
static constexpr int OFF_VMAT  = OFF_UMAT + 512*64;
static constexpr int OFF_GU    = OFF_VMAT + 512*64;   // 64*64
static constexpr int OFF_GV    = OFF_GU + 64*64;
static constexpr int OFF_A     = OFF_GV + 64*64;      // 512*64
static constexpr int OFF_R     = OFF_A + 512*64;      // 64*512
static constexpr int OFF_C     = OFF_R + 64*512;      // 64*64
static constexpr int OFF_F     = OFF_C + 64*64;       // 64*512
static constexpr int OFF_W     = OFF_F + 64*512;      // 512*512 fp32
// Wt (bf16, 512*512 = 512 KB = 131072 float-slots) OVERLAYS offset 0: by the
// time k_Wt runs, sigma/beta/Umat/Vmat/G are all dead. Written fresh each launch.
static constexpr int OFF_WT    = 0;

__device__ inline unsigned short f2bf_rne(float f) {
    union { float f; unsigned u; } v; v.f = f;
    return (unsigned short)((v.u + 0x7FFFu + ((v.u >> 16) & 1u)) >> 16);
}

// ---------------------------------------------------------------------------
// pack reflectors (zero leading entries), beta = 2/(u.u), sigma
__global__ void k_pack(const float* __restrict__ U, const float* __restrict__ V,
                       const float* __restrict__ p, float* __restrict__ ws) {
    int b = blockIdx.x;
    int t = threadIdx.x;
    float* sigma = ws + OFF_SIGMA;
    if (b == 128) {
        for (int c = t; c < INSIZE; c += 256) {
            float pv = p[c];
            float s = 1.0f / (1.0f + expf(-pv));
            sigma[c] = 0.55f + 0.9f * (s - 0.5f);   // SIGMA_MIN=0.1, MAX=1.0
        }
        return;
    }
    bool isV = (b >= 64);
    int i = isV ? (b - 64) : b;      // packed column index (scan order)
    int row = isV ? (63 - i) : i;    // source row: V scan is reversed
    const float* src = isV ? V : U;
    float* dst = ws + (isV ? OFF_VMAT : OFF_UMAT);
    float partial = 0.f;
    for (int r = t; r < INSIZE; r += 256) {
        float v = (r >= row) ? src[row * INSIZE + r] : 0.0f;  // triu
        dst[r * NREF + i] = v;
        partial += v * v;
    }
    __shared__ float red[256];
    red[t] = partial;
    __syncthreads();
    for (int s = 128; s > 0; s >>= 1) {
        if (t < s) red[t] += red[t + s];
        __syncthreads();
    }
    if (t == 0) (ws + (isV ? OFF_BETAV : OFF_BETAU))[i] = 2.0f / red[0];
}

// ---------------------------------------------------------------------------
// Gram matrices G[i][j] = col_i . col_j  (one wave per entry)
__global__ void k_gram(float* __restrict__ ws) {
    int bid = blockIdx.x;            // 0..8191
    int z = bid >> 12;               // 0=U, 1=V
    int rem = bid & 4095;
    int i = rem >> 6, j = rem & 63;
    const float* M = ws + (z ? OFF_VMAT : OFF_UMAT);
    float* G = ws + (z ? OFF_GV : OFF_GU);
    int t = threadIdx.x;             // 64 threads
    float s = 0.f;
    for (int r = t; r < INSIZE; r += 64)
        s += M[r * NREF + i] * M[r * NREF + j];
    for (int o = 32; o > 0; o >>= 1) s += __shfl_down(s, o, 64);
    if (t == 0) G[i * 64 + j] = s;
}

// ---------------------------------------------------------------------------
// A and R via register-resident substitution (replaces T build entirely).
// block 0: A (thread r owns row r of A);  block 1: R (thread c owns col c of R)
__global__ __launch_bounds__(512) void k_AR(float* __restrict__ ws) {
    __shared__ float Gs[64 * 64];
    __shared__ float bs[64];
    int z = blockIdx.x;
    int t = threadIdx.x;             // 0..511
    const float* G = ws + (z ? OFF_GV : OFF_GU);
    const float* beta = ws + (z ? OFF_BETAV : OFF_BETAU);
    for (int i = t; i < 4096; i += 512) Gs[i] = G[i];
    if (t < 64) bs[t] = beta[t];
    __syncthreads();
    float acc[64];
    if (z == 0) {
        const float* Um = ws + OFF_UMAT;     // [r*64 + i]
        float* A = ws + OFF_A;
#pragma unroll
        for (int j = 0; j < 64; ++j) {
            float s = Um[t * NREF + j];
#pragma unroll
            for (int m = 0; m < j; ++m) s -= acc[m] * Gs[m * 64 + j];
            acc[j] = s * bs[j];
        }
#pragma unroll
        for (int j = 0; j < 64; ++j) A[t * NREF + j] = acc[j];
    } else {
        const float* Vm = ws + OFF_VMAT;
        float* R = ws + OFF_R;
#pragma unroll
        for (int i = 63; i >= 0; --i) {
            float s = Vm[t * NREF + i];
#pragma unroll
            for (int m = i + 1; m < 64; ++m) s -= Gs[i * 64 + m] * acc[m];
            acc[i] = s * bs[i];
        }
#pragma unroll
        for (int i = 0; i < 64; ++i) R[i * INSIZE + t] = acc[i];
    }
}

// ---------------------------------------------------------------------------
// C[i,j] = sum_c U[c,i] sig[c] V[c,j]
__global__ void k_C(float* __restrict__ ws) {
    int idx = blockIdx.x * 256 + threadIdx.x;   // 4096
    int i = idx >> 6, j = idx & 63;
    const float* Um = ws + OFF_UMAT;
    const float* Vm = ws + OFF_VMAT;
    const float* sig = ws + OFF_SIGMA;
    float s = 0.f;
    for (int c = 0; c < INSIZE; ++c)
        s += Um[c * NREF + i] * sig[c] * Vm[c * NREF + j];
    (ws + OFF_C)[idx] = s;
}

// ---------------------------------------------------------------------------
// F[i,c] = U[c,i]*sig[c] - sum_m C[i,m] R[m,c]
__global__ void k_F(float* __restrict__ ws) {
    int idx = blockIdx.x * 256 + threadIdx.x;
    int i = idx >> 9, c = idx & 511;
    const float* C = ws + OFF_C;
    const float* R = ws + OFF_R;
    float s = (ws + OFF_UMAT)[c * NREF + i] * (ws + OFF_SIGMA)[c];
    float acc = 0.f;
    for (int m = 0; m < 64; ++m) acc += C[i * 64 + m] * R[m * INSIZE + c];
    (ws + OFF_F)[i * INSIZE + c] = s - acc;
}

// ---------------------------------------------------------------------------
// W[r,c] = sig_r*(r==c) - sum_i A[r,i]F[i,c] - sig_r * sum_i V[r,i]R[i,c]
__global__ void k_W(float* __restrict__ ws) {
    int idx = blockIdx.x * 256 + threadIdx.x;
    int r = idx >> 9, c = idx & 511;
    const float* A = ws + OFF_A;
    const float* F = ws + OFF_F;
    const float* Vm = ws + OFF_VMAT;
    const float* R = ws + OFF_R;
    float sig = (ws + OFF_SIGMA)[r];
    float acc1 = 0.f, acc2 = 0.f;
    for (int i = 0; i < 64; ++i) {
        acc1 += A[r * NREF + i] * F[i * INSIZE + c];
        acc2 += Vm[r * NREF + i] * R[i * INSIZE + c];
    }
    float w = -acc1 - sig * acc2;
    if (r == c) w += sig;
    (ws + OFF_W)[r * INSIZE + c] = w;
}

// ---------------------------------------------------------------------------
// Wt[c*512 + r] = bf16(W[r*512 + c])  -- transposed, for MFMA B-operand
__global__ __launch_bounds__(256) void k_Wt(float* __restrict__ ws) {
    __shared__ float tile[32][33];
    int bx = blockIdx.x & 15;        // c-tile
    int by = blockIdx.x >> 4;        // r-tile
    int t = threadIdx.x;
    int lr = t >> 5, lc = t & 31;
    const float* W = ws + OFF_W;
    unsigned short* Wt = (unsigned short*)(ws + OFF_WT);
#pragma unroll
    for (int i = 0; i < 4; ++i)
        tile[lr + i * 8][lc] = W[(by * 32 + lr + i * 8) * INSIZE + bx * 32 + lc];
    __syncthreads();
#pragma unroll
    for (int i = 0; i < 4; ++i) {
        float f = tile[lc][lr + i * 8];   // transposed read, stride-33: no conflicts
        Wt[(bx * 32 + lr + i * 8) * INSIZE + by * 32 + lc] = f2bf_rne(f);
    }
}

// ---------------------------------------------------------------------------
// out = x @ W + bias : bf16 MFMA, 128x128 block tile, BK=32.
// A staged fp32 via global_load_lds (chunk-XOR swizzle), converted to bf16 at
// frag build. B = Wt rows staged bf16 via global_load_lds (chunk-XOR swizzle).
// Verified gfx950 layouts (mfma_f32_16x16x32_bf16):
//   A: m=lane&15, k=(lane>>4)*8+j ; B: n=lane&15, k=(lane>>4)*8+j
//   C/D: col=lane&15, row=(lane>>4)*4+reg
typedef __attribute__((ext_vector_type(8))) short short8;
typedef __attribute__((ext_vector_type(4))) float float4v;

__global__ __launch_bounds__(256) void k_gemm(const float* __restrict__ X,
                                              const float* __restrict__ ws,
                                              const float* __restrict__ bias,
                                              float* __restrict__ out) {
    __shared__ float As[128 * 32];              // 16 KB, chunk-swizzled
    __shared__ unsigned short Bs[128 * 32];     // 8 KB, chunk-swizzled
    const unsigned short* Wt = (const unsigned short*)(ws + OFF_WT);

    // XCD co-location: the 4 blocks sharing an X row-panel land on one XCD.
    int L = blockIdx.x;              // 0..255
    int jj = L >> 3, x = L & 7;
    int bn = jj & 3;
    int bm = (jj >> 2) * 8 + x;
    int row0 = bm * 128, col0 = bn * 128;

    int t = threadIdx.x;
    int l = t & 63, w = t >> 6;
    int wm = (w >> 1) * 64, wn = (w & 1) * 64;

    float4v acc[4][4] = {};

    int quad = l >> 4;
    int lan = l & 15;

    for (int k0 = 0; k0 < INSIZE; k0 += 32) {
        __syncthreads();   // previous iter's frag reads done before overwrite
        // ---- stage A tile: 128 rows x 32 k fp32. physical chunk P holds
        // logical (row=P>>3, kchunk=(P&7)^(row&7)); lane->LDS is contiguous.
#pragma unroll
        for (int i = 0; i < 4; ++i) {
            int P = i * 256 + t;
            int prow = P >> 3, pc = P & 7;
            int lc = pc ^ (prow & 7);
            const float* g = X + (size_t)(row0 + prow) * INSIZE + k0 + lc * 4;
            __builtin_amdgcn_global_load_lds(
                (const __attribute__((address_space(1))) void*)g,
                (__attribute__((address_space(3))) void*)(As + P * 4), 16, 0, 0);
        }
        // ---- stage B tile: 128 n-rows x 32 k bf16 from Wt.
#pragma unroll
        for (int i = 0; i < 2; ++i) {
            int P = i * 256 + t;
            int prow = P >> 2, pc = P & 3;
            int lc = pc ^ ((prow >> 1) & 3);
            const unsigned short* g = Wt + (size_t)(col0 + prow) * INSIZE + k0 + lc * 8;
            __builtin_amdgcn_global_load_lds(
                (const __attribute__((address_space(1))) void*)g,
                (__attribute__((address_space(3))) void*)(Bs + P * 8), 16, 0, 0);
        }
        __syncthreads();   // compiler drains vmcnt before s_barrier

        // ---- build fragments
        short8 af[4];
        short8 bf[4];
#pragma unroll
        for (int mi = 0; mi < 4; ++mi) {
            int rl = wm + mi * 16 + lan;
            int c0 = quad * 2;
            const float4v lo = *(const float4v*)(As + (rl * 8 + (c0 ^ (rl & 7))) * 4);
            const float4v hi = *(const float4v*)(As + (rl * 8 + ((c0 + 1) ^ (rl & 7))) * 4);
            union { short8 s; __hip_bfloat162 h[4]; } u;
            u.h[0] = __float22bfloat162_rn(make_float2(lo[0], lo[1]));
            u.h[1] = __float22bfloat162_rn(make_float2(lo[2], lo[3]));
            u.h[2] = __float22bfloat162_rn(make_float2(hi[0], hi[1]));
            u.h[3] = __float22bfloat162_rn(make_float2(hi[2], hi[3]));
            af[mi] = u.s;
        }
#pragma unroll
        for (int ni = 0; ni < 4; ++ni) {
            int rn = wn + ni * 16 + lan;
            int c = quad ^ ((rn >> 1) & 3);
            bf[ni] = *(const short8*)(Bs + (rn * 4 + c) * 8);
        }
#pragma unroll
        for (int mi = 0; mi < 4; ++mi)
#pragma unroll
            for (int ni = 0; ni < 4; ++ni)
                acc[mi][ni] = __builtin_amdgcn_mfma_f32_16x16x32_bf16(
                    af[mi], bf[ni], acc[mi][ni], 0, 0, 0);
    }

    // ---- epilogue: C/D col=lan, row=quad*4+reg
#pragma unroll
    for (int ni = 0; ni < 4; ++ni) {
        int c = col0 + wn + ni * 16 + lan;
        float bv = bias[c];
#pragma unroll
        for (int mi = 0; mi < 4; ++mi) {
            int rbase = row0 + wm + mi * 16 + quad * 4;
#pragma unroll
            for (int r = 0; r < 4; ++r)
                out[(size_t)(rbase + r) * INSIZE + c] = acc[mi][ni][r] + bv;
        }
    }
}

// ---------------------------------------------------------------------------
extern "C" void kernel_launch(void* const* d_in, const int* in_sizes, int n_in,
                              void* d_out, int out_size, void* d_ws, size_t ws_size,
                              hipStream_t stream) {
    const float* x    = (const float*)d_in[0];
    const float* p    = (const float*)d_in[1];
    const float* U    = (const float*)d_in[2];
    const float* V    = (const float*)d_in[3];
    const float* bias = (const float*)d_in[4];
    float* ws  = (float*)d_ws;
    float* out = (float*)d_out;

    k_pack<<<129, 256, 0, stream>>>(U, V, p, ws);
    k_gram<<<8192, 64, 0, stream>>>(ws);
    k_AR<<<2, 512, 0, stream>>>(ws);
    k_C<<<16, 256, 0, stream>>>(ws);
    k_F<<<128, 256, 0, stream>>>(ws);
    k_W<<<1024, 256, 0, stream>>>(ws);
    k_Wt<<<256, 256, 0, stream>>>(ws);
    k_gemm<<<256, 256, 0, stream>>>(x, ws, bias, out);
}

// Round 3
// 136.318 us; speedup vs baseline: 2.7882x; 1.2347x over previous
//
#include <hip/hip_runtime.h>
#include <hip/hip_bf16.h>
#include <math.h>

// SpectralLinear: out = x @ (M_U * diag(sigma) * M_V) + bias
// M_U = H(u0)...H(u63), M_V = H(v63)...H(v0), H(u) = I - (2/u.u) u u^T
// Compact WY without explicit T:  T^{-1} = strict_upper(G) + diag(1/beta)
//   A = Umat*T_U  (forward subst)   R = T_V*Vmat^T  (backward subst)
//   C = (Umat^T S) Vmat
//   W = S - SV*R - A*F  =  S - [A | E] . [SU^T ; R],  E = SV - A*C
// NOTE: inputs U,V are already upper-triangular (setup applies jnp.triu), so
// raw rows ARE the reflectors: Umat[r,i] = U[i,r], Vmat[r,i] = V[63-i,r].
// out = x @ W + bias via bf16 MFMA (Wt = W^T in bf16; fp32 accumulate).

#define INSIZE 512
#define NREF 64
#define BATCH 8192

// workspace layout (float slots)
static constexpr int OFF_WT    = 0;                    // 512*512 bf16 = 131072 slots
static constexpr int OFF_SIGMA = 131072;               // 512
static constexpr int OFF_BETAU = OFF_SIGMA + 512;      // 64
static constexpr int OFF_BETAV = OFF_BETAU + 64;       // 64
static constexpr int OFF_GU    = OFF_BETAV + 64;       // 64*64
static constexpr int OFF_GV    = OFF_GU + 4096;        // 64*64
static constexpr int OFF_C     = OFF_GV + 4096;        // 64*64
static constexpr int OFF_PT    = OFF_C + 4096;         // 128*512: At rows 0..63, Et rows 64..127
static constexpr int OFF_R     = OFF_PT + 128 * 512;   // 64*512

__device__ inline float sigma_of(float pv) {
    float s = 1.0f / (1.0f + expf(-pv));
    return 0.55f + 0.9f * (s - 0.5f);   // SIGMA_MIN=0.1, SIGMA_MAX=1.0
}

// ---------------------------------------------------------------------------
// k_prep: blocks 0..63  -> G_U row i (+beta_U[i])
//         blocks 64..127-> G_V row i (+beta_V[i])   (G of packed cols: row 63-i)
//         blocks 128..191-> C row i:  C[i,j] = sum_c U[i,c] sig_c V[63-j,c]
//         block 192     -> sigma array
__global__ __launch_bounds__(256) void k_prep(const float* __restrict__ U,
                                              const float* __restrict__ V,
                                              const float* __restrict__ p,
                                              float* __restrict__ ws) {
    int b = blockIdx.x, t = threadIdx.x;
    if (b == 192) {
        for (int c = t; c < INSIZE; c += 256)
            (ws + OFF_SIGMA)[c] = sigma_of(p[c]);
        return;
    }
    __shared__ float rowi[INSIZE];
    int w = t >> 6, l = t & 63;
    if (b < 128) {
        bool isV = (b >= 64);
        int i = isV ? (b - 64) : b;
        const float* src = isV ? V : U;
        int srow = isV ? (63 - i) : i;
        for (int c = t; c < INSIZE; c += 256) rowi[c] = src[srow * INSIZE + c];
        __syncthreads();
        float* G = ws + (isV ? OFF_GV : OFF_GU);
        float* beta = ws + (isV ? OFF_BETAV : OFF_BETAU);
        for (int jj = 0; jj < 16; ++jj) {
            int j = w * 16 + jj;
            int jrow = isV ? (63 - j) : j;
            const float* rj = src + jrow * INSIZE;
            float s = 0.f;
            for (int c = l; c < INSIZE; c += 64) s += rowi[c] * rj[c];
            for (int o = 32; o > 0; o >>= 1) s += __shfl_down(s, o, 64);
            if (l == 0) {
                G[i * 64 + j] = s;
                if (j == i) beta[i] = 2.0f / s;
            }
        }
    } else {
        int i = b - 128;
        for (int c = t; c < INSIZE; c += 256)
            rowi[c] = U[i * INSIZE + c] * sigma_of(p[c]);
        __syncthreads();
        float* C = ws + OFF_C;
        for (int jj = 0; jj < 16; ++jj) {
            int j = w * 16 + jj;
            const float* rj = V + (63 - j) * INSIZE;
            float s = 0.f;
            for (int c = l; c < INSIZE; c += 64) s += rowi[c] * rj[c];
            for (int o = 32; o > 0; o >>= 1) s += __shfl_down(s, o, 64);
            if (l == 0) C[i * 64 + j] = s;
        }
    }
}

// ---------------------------------------------------------------------------
// A and R via register-resident substitution.
// block 0: At[j, t] = A[t, j]  (forward)   block 1: R[i, t]  (backward)
__global__ __launch_bounds__(512) void k_AR(const float* __restrict__ U,
                                            const float* __restrict__ V,
                                            float* __restrict__ ws) {
    __shared__ float Gs[64 * 64];
    __shared__ float bs[64];
    int z = blockIdx.x;
    int t = threadIdx.x;             // 0..511
    const float* G = ws + (z ? OFF_GV : OFF_GU);
    const float* beta = ws + (z ? OFF_BETAV : OFF_BETAU);
    for (int i = t; i < 4096; i += 512) Gs[i] = G[i];
    if (t < 64) bs[t] = beta[t];
    __syncthreads();
    float acc[64];
    if (z == 0) {
        float* At = ws + OFF_PT;     // rows 0..63 of PT
#pragma unroll
        for (int j = 0; j < 64; ++j) {
            float s = U[j * INSIZE + t];          // Umat[t,j], coalesced
#pragma unroll
            for (int m = 0; m < j; ++m) s -= acc[m] * Gs[m * 64 + j];
            acc[j] = s * bs[j];
        }
#pragma unroll
        for (int j = 0; j < 64; ++j) At[j * INSIZE + t] = acc[j];
    } else {
        float* R = ws + OFF_R;
#pragma unroll
        for (int i = 63; i >= 0; --i) {
            float s = V[(63 - i) * INSIZE + t];   // Vmat[t,i], coalesced
#pragma unroll
            for (int m = i + 1; m < 64; ++m) s -= Gs[i * 64 + m] * acc[m];
            acc[i] = s * bs[i];
        }
#pragma unroll
        for (int i = 0; i < 64; ++i) R[i * INSIZE + t] = acc[i];
    }
}

// ---------------------------------------------------------------------------
// Et[j, r] = sig_r * V[63-j, r] - sum_i At[i, r] * C[i, j]   (rows 64..127 of PT)
__global__ __launch_bounds__(256) void k_E(const float* __restrict__ V,
                                           float* __restrict__ ws) {
    int b = blockIdx.x, t = threadIdx.x;
    int j = (b & 15) * 4 + (t >> 6);
    int r = (b >> 4) * 64 + (t & 63);
    const float* At = ws + OFF_PT;
    const float* C = ws + OFF_C;
    float e = (ws + OFF_SIGMA)[r] * V[(63 - j) * INSIZE + r];
#pragma unroll 8
    for (int i = 0; i < 64; ++i)
        e -= At[i * INSIZE + r] * C[i * 64 + j];
    (ws + OFF_PT)[(64 + j) * INSIZE + r] = e;
}

// ---------------------------------------------------------------------------
// Fused W build + transpose + bf16 cast:
//   W[r,c] = (r==c)*sig_r - sum_{k<128} PT[k,r]*Q[k,c]
//   Q[k,c] = (k<64) ? U[k,c]*sig_c : R[k-64,c]
//   Wt[c*512+r] = bf16(W[r,c])
// 256 blocks (16x16 grid of 32x32 tiles), 2x2 micro-tile per thread.
__global__ __launch_bounds__(256) void k_Wt(const float* __restrict__ U,
                                            float* __restrict__ ws) {
    __shared__ float Ps[128][34];
    __shared__ float Qs[128][34];
    int t = threadIdx.x;
    int r0 = (blockIdx.x >> 4) * 32;
    int c0 = (blockIdx.x & 15) * 32;
    const float* PT = ws + OFF_PT;
    const float* R = ws + OFF_R;
    const float* sig = ws + OFF_SIGMA;
    int lr = t & 31, kb = t >> 5;         // kb 0..7
    float sc = sig[c0 + lr];
#pragma unroll
    for (int ii = 0; ii < 16; ++ii) {
        int k = kb + ii * 8;
        Ps[k][lr] = PT[k * INSIZE + r0 + lr];
        Qs[k][lr] = (k < 64) ? U[k * INSIZE + c0 + lr] * sc
                             : R[(k - 64) * INSIZE + c0 + lr];
    }
    __syncthreads();
    int ty = t >> 4, tx = t & 15;
    float a00 = 0.f, a01 = 0.f, a10 = 0.f, a11 = 0.f;
#pragma unroll
    for (int k = 0; k < 128; ++k) {
        float2 a = *(const float2*)&Ps[k][ty * 2];
        float2 bq = *(const float2*)&Qs[k][tx * 2];
        a00 += a.x * bq.x; a01 += a.x * bq.y;
        a10 += a.y * bq.x; a11 += a.y * bq.y;
    }
    int rg = r0 + ty * 2, cg = c0 + tx * 2;
    float w00 = ((rg == cg) ? sig[rg] : 0.f) - a00;
    float w01 = ((rg == cg + 1) ? sig[rg] : 0.f) - a01;
    float w10 = ((rg + 1 == cg) ? sig[rg + 1] : 0.f) - a10;
    float w11 = ((rg + 1 == cg + 1) ? sig[rg + 1] : 0.f) - a11;
    unsigned short* Wt = (unsigned short*)(ws + OFF_WT);
    __hip_bfloat162 lo = __float22bfloat162_rn(make_float2(w00, w10));
    __hip_bfloat162 hi = __float22bfloat162_rn(make_float2(w01, w11));
    *(__hip_bfloat162*)&Wt[cg * INSIZE + rg] = lo;
    *(__hip_bfloat162*)&Wt[(cg + 1) * INSIZE + rg] = hi;
}

// ---------------------------------------------------------------------------
// out = x @ W + bias : bf16 MFMA, 128x128 block tile, BK=32.  (validated R2)
typedef __attribute__((ext_vector_type(8))) short short8;
typedef __attribute__((ext_vector_type(4))) float float4v;

__global__ __launch_bounds__(256) void k_gemm(const float* __restrict__ X,
                                              const float* __restrict__ ws,
                                              const float* __restrict__ bias,
                                              float* __restrict__ out) {
    __shared__ float As[128 * 32];              // 16 KB, chunk-swizzled
    __shared__ unsigned short Bs[128 * 32];     // 8 KB, chunk-swizzled
    const unsigned short* Wt = (const unsigned short*)(ws + OFF_WT);

    int L = blockIdx.x;              // 0..255
    int jj = L >> 3, x = L & 7;
    int bn = jj & 3;
    int bm = (jj >> 2) * 8 + x;
    int row0 = bm * 128, col0 = bn * 128;

    int t = threadIdx.x;
    int l = t & 63, w = t >> 6;
    int wm = (w >> 1) * 64, wn = (w & 1) * 64;

    float4v acc[4][4] = {};
    int quad = l >> 4;
    int lan = l & 15;

    for (int k0 = 0; k0 < INSIZE; k0 += 32) {
        __syncthreads();
#pragma unroll
        for (int i = 0; i < 4; ++i) {
            int P = i * 256 + t;
            int prow = P >> 3, pc = P & 7;
            int lc = pc ^ (prow & 7);
            const float* g = X + (size_t)(row0 + prow) * INSIZE + k0 + lc * 4;
            __builtin_amdgcn_global_load_lds(
                (const __attribute__((address_space(1))) void*)g,
                (__attribute__((address_space(3))) void*)(As + P * 4), 16, 0, 0);
        }
#pragma unroll
        for (int i = 0; i < 2; ++i) {
            int P = i * 256 + t;
            int prow = P >> 2, pc = P & 3;
            int lc = pc ^ ((prow >> 1) & 3);
            const unsigned short* g = Wt + (size_t)(col0 + prow) * INSIZE + k0 + lc * 8;
            __builtin_amdgcn_global_load_lds(
                (const __attribute__((address_space(1))) void*)g,
                (__attribute__((address_space(3))) void*)(Bs + P * 8), 16, 0, 0);
        }
        __syncthreads();

        short8 af[4];
        short8 bf[4];
#pragma unroll
        for (int mi = 0; mi < 4; ++mi) {
            int rl = wm + mi * 16 + lan;
            int c0q = quad * 2;
            const float4v lo = *(const float4v*)(As + (rl * 8 + (c0q ^ (rl & 7))) * 4);
            const float4v hi = *(const float4v*)(As + (rl * 8 + ((c0q + 1) ^ (rl & 7))) * 4);
            union { short8 s; __hip_bfloat162 h[4]; } u;
            u.h[0] = __float22bfloat162_rn(make_float2(lo[0], lo[1]));
            u.h[1] = __float22bfloat162_rn(make_float2(lo[2], lo[3]));
            u.h[2] = __float22bfloat162_rn(make_float2(hi[0], hi[1]));
            u.h[3] = __float22bfloat162_rn(make_float2(hi[2], hi[3]));
            af[mi] = u.s;
        }
#pragma unroll
        for (int ni = 0; ni < 4; ++ni) {
            int rn = wn + ni * 16 + lan;
            int c = quad ^ ((rn >> 1) & 3);
            bf[ni] = *(const short8*)(Bs + (rn * 4 + c) * 8);
        }
#pragma unroll
        for (int mi = 0; mi < 4; ++mi)
#pragma unroll
            for (int ni = 0; ni < 4; ++ni)
                acc[mi][ni] = __builtin_amdgcn_mfma_f32_16x16x32_bf16(
                    af[mi], bf[ni], acc[mi][ni], 0, 0, 0);
    }

#pragma unroll
    for (int ni = 0; ni < 4; ++ni) {
        int c = col0 + wn + ni * 16 + lan;
        float bv = bias[c];
#pragma unroll
        for (int mi = 0; mi < 4; ++mi) {
            int rbase = row0 + wm + mi * 16 + quad * 4;
#pragma unroll
            for (int r = 0; r < 4; ++r)
                out[(size_t)(rbase + r) * INSIZE + c] = acc[mi][ni][r] + bv;
        }
    }
}

// ---------------------------------------------------------------------------
extern "C" void kernel_launch(void* const* d_in, const int* in_sizes, int n_in,
                              void* d_out, int out_size, void* d_ws, size_t ws_size,
                              hipStream_t stream) {
    const float* x    = (const float*)d_in[0];
    const float* p    = (const float*)d_in[1];
    const float* U    = (const float*)d_in[2];
    const float* V    = (const float*)d_in[3];
    const float* bias = (const float*)d_in[4];
    float* ws  = (float*)d_ws;
    float* out = (float*)d_out;

    k_prep<<<193, 256, 0, stream>>>(U, V, p, ws);
    k_AR<<<2, 512, 0, stream>>>(U, V, ws);
    k_E<<<128, 256, 0, stream>>>(V, ws);
    k_Wt<<<256, 256, 0, stream>>>(U, ws);
    k_gemm<<<256, 256, 0, stream>>>(x, ws, bias, out);
}

// Round 4
// 130.032 us; speedup vs baseline: 2.9230x; 1.0483x over previous
//
#include <hip/hip_runtime.h>
#include <hip/hip_bf16.h>
#include <math.h>

// SpectralLinear: out = x @ (M_U * diag(sigma) * M_V) + bias
// Compact WY without explicit T:  T^{-1} = strict_upper(G) + diag(1/beta)
//   A = Umat*T_U (forward subst)   R = T_V*Vmat^T (backward subst)
//   C = (Umat^T S) Vmat ;  E = SV - A*C
//   W = S - [A | E] . [SU^T ; R]
// Inputs U,V are already upper-triangular (setup applies jnp.triu):
//   Umat[r,i] = U[i,r], Vmat[r,i] = V[63-i,r].
// out = x @ W + bias via bf16 MFMA (Wt = W^T bf16; fp32 accumulate).

#define INSIZE 512
#define NREF 64
#define BATCH 8192

// workspace layout (float slots)
static constexpr int OFF_WT    = 0;                    // 512*512 bf16 = 131072 slots
static constexpr int OFF_SIGMA = 131072;               // 512
static constexpr int OFF_BETAU = OFF_SIGMA + 512;      // 64
static constexpr int OFF_BETAV = OFF_BETAU + 64;       // 64
static constexpr int OFF_GU    = OFF_BETAV + 64;       // 64*64
static constexpr int OFF_GV    = OFF_GU + 4096;        // 64*64
static constexpr int OFF_C     = OFF_GV + 4096;        // 64*64
static constexpr int OFF_PT    = OFF_C + 4096;         // 64*512 (At rows only)
static constexpr int OFF_R     = OFF_PT + 128 * 512;   // 64*512

__device__ inline float sigma_of(float pv) {
    float s = 1.0f / (1.0f + expf(-pv));
    return 0.55f + 0.9f * (s - 0.5f);   // SIGMA_MIN=0.1, SIGMA_MAX=1.0
}

// ---------------------------------------------------------------------------
// k_prep: blocks 0..63   -> G_U row i (+beta_U[i])
//         blocks 64..127 -> G_V row i (+beta_V[i])  (packed order: row 63-i)
//         blocks 128..191-> C row i:  C[i,j] = sum_c U[i,c] sig_c V[63-j,c]
//         block 192      -> sigma array
__global__ __launch_bounds__(256) void k_prep(const float* __restrict__ U,
                                              const float* __restrict__ V,
                                              const float* __restrict__ p,
                                              float* __restrict__ ws) {
    int b = blockIdx.x, t = threadIdx.x;
    if (b == 192) {
        for (int c = t; c < INSIZE; c += 256)
            (ws + OFF_SIGMA)[c] = sigma_of(p[c]);
        return;
    }
    __shared__ float rowi[INSIZE];
    int w = t >> 6, l = t & 63;
    if (b < 128) {
        bool isV = (b >= 64);
        int i = isV ? (b - 64) : b;
        const float* src = isV ? V : U;
        int srow = isV ? (63 - i) : i;
        for (int c = t; c < INSIZE; c += 256) rowi[c] = src[srow * INSIZE + c];
        __syncthreads();
        float* G = ws + (isV ? OFF_GV : OFF_GU);
        float* beta = ws + (isV ? OFF_BETAV : OFF_BETAU);
        for (int jj = 0; jj < 16; ++jj) {
            int j = w * 16 + jj;
            int jrow = isV ? (63 - j) : j;
            const float* rj = src + jrow * INSIZE;
            float s = 0.f;
            for (int c = l; c < INSIZE; c += 64) s += rowi[c] * rj[c];
            for (int o = 32; o > 0; o >>= 1) s += __shfl_down(s, o, 64);
            if (l == 0) {
                G[i * 64 + j] = s;
                if (j == i) beta[i] = 2.0f / s;
            }
        }
    } else {
        int i = b - 128;
        for (int c = t; c < INSIZE; c += 256)
            rowi[c] = U[i * INSIZE + c] * sigma_of(p[c]);
        __syncthreads();
        float* C = ws + OFF_C;
        for (int jj = 0; jj < 16; ++jj) {
            int j = w * 16 + jj;
            const float* rj = V + (63 - j) * INSIZE;
            float s = 0.f;
            for (int c = l; c < INSIZE; c += 64) s += rowi[c] * rj[c];
            for (int o = 32; o > 0; o >>= 1) s += __shfl_down(s, o, 64);
            if (l == 0) C[i * 64 + j] = s;
        }
    }
}

// ---------------------------------------------------------------------------
// A and R via register-resident substitution.
// block 0: At[j, t] = A[t, j]  (forward)   block 1: R[i, t]  (backward)
__global__ __launch_bounds__(512) void k_AR(const float* __restrict__ U,
                                            const float* __restrict__ V,
                                            float* __restrict__ ws) {
    __shared__ float Gs[64 * 64];
    __shared__ float bs[64];
    int z = blockIdx.x;
    int t = threadIdx.x;             // 0..511
    const float* G = ws + (z ? OFF_GV : OFF_GU);
    const float* beta = ws + (z ? OFF_BETAV : OFF_BETAU);
    for (int i = t; i < 4096; i += 512) Gs[i] = G[i];
    if (t < 64) bs[t] = beta[t];
    __syncthreads();
    float acc[64];
    if (z == 0) {
        float* At = ws + OFF_PT;
#pragma unroll
        for (int j = 0; j < 64; ++j) {
            float s = U[j * INSIZE + t];          // Umat[t,j], coalesced
#pragma unroll
            for (int m = 0; m < j; ++m) s -= acc[m] * Gs[m * 64 + j];
            acc[j] = s * bs[j];
        }
#pragma unroll
        for (int j = 0; j < 64; ++j) At[j * INSIZE + t] = acc[j];
    } else {
        float* R = ws + OFF_R;
#pragma unroll
        for (int i = 63; i >= 0; --i) {
            float s = V[(63 - i) * INSIZE + t];   // Vmat[t,i], coalesced
#pragma unroll
            for (int m = i + 1; m < 64; ++m) s -= Gs[i * 64 + m] * acc[m];
            acc[i] = s * bs[i];
        }
#pragma unroll
        for (int i = 0; i < 64; ++i) R[i * INSIZE + t] = acc[i];
    }
}

// ---------------------------------------------------------------------------
// Fused E + W build + transpose + bf16 cast (per 32x32 output tile):
//   Ps rows 0..63  = At tile (loaded)
//   Ps rows 64..127= Et tile computed in-LDS: Et[j,r] = sig_r V[63-j,r] - sum_i At[i,r] C[i,j]
//   Q[k,c] = (k<64) ? U[k,c]*sig_c : R[k-64,c]
//   W[r,c] = (r==c)*sig_r - sum_{k<128} Ps[k][r]*Qs[k][c];  Wt[c*512+r]=bf16(W[r,c])
__global__ __launch_bounds__(256) void k_WtE(const float* __restrict__ U,
                                             const float* __restrict__ V,
                                             float* __restrict__ ws) {
    __shared__ float Ps[128][34];
    __shared__ float Qs[128][34];
    __shared__ float Cs[4096];
    int t = threadIdx.x;
    int r0 = (blockIdx.x >> 4) * 32;
    int c0 = (blockIdx.x & 15) * 32;
    const float* At = ws + OFF_PT;
    const float* R = ws + OFF_R;
    const float* sig = ws + OFF_SIGMA;
    int lr = t & 31, kb = t >> 5;         // kb 0..7
    float sc = sig[c0 + lr];
#pragma unroll
    for (int ii = 0; ii < 8; ++ii) {
        int k = kb + ii * 8;              // 0..63
        Ps[k][lr] = At[k * INSIZE + r0 + lr];
    }
#pragma unroll
    for (int ii = 0; ii < 16; ++ii) {
        int k = kb + ii * 8;
        Qs[k][lr] = (k < 64) ? U[k * INSIZE + c0 + lr] * sc
                             : R[(k - 64) * INSIZE + c0 + lr];
    }
#pragma unroll
    for (int i = 0; i < 16; ++i) Cs[t + i * 256] = (ws + OFF_C)[t + i * 256];
    __syncthreads();
    // ---- Et phase: 8 j's per thread, reads Ps rows 0..63, writes rows 64..127
    float sr = sig[r0 + lr];
#pragma unroll
    for (int ii = 0; ii < 8; ++ii) {
        int j = kb * 8 + ii;              // 0..63
        float e = sr * V[(63 - j) * INSIZE + r0 + lr];
#pragma unroll 8
        for (int i = 0; i < 64; ++i)
            e -= Ps[i][lr] * Cs[i * 64 + j];
        Ps[64 + j][lr] = e;
    }
    __syncthreads();
    // ---- 32x32x128 GEMM, 2x2 per thread
    int ty = t >> 4, tx = t & 15;
    float a00 = 0.f, a01 = 0.f, a10 = 0.f, a11 = 0.f;
#pragma unroll
    for (int k = 0; k < 128; ++k) {
        float2 a = *(const float2*)&Ps[k][ty * 2];
        float2 bq = *(const float2*)&Qs[k][tx * 2];
        a00 += a.x * bq.x; a01 += a.x * bq.y;
        a10 += a.y * bq.x; a11 += a.y * bq.y;
    }
    int rg = r0 + ty * 2, cg = c0 + tx * 2;
    float w00 = ((rg == cg) ? sig[rg] : 0.f) - a00;
    float w01 = ((rg == cg + 1) ? sig[rg] : 0.f) - a01;
    float w10 = ((rg + 1 == cg) ? sig[rg + 1] : 0.f) - a10;
    float w11 = ((rg + 1 == cg + 1) ? sig[rg + 1] : 0.f) - a11;
    unsigned short* Wt = (unsigned short*)(ws + OFF_WT);
    __hip_bfloat162 lo = __float22bfloat162_rn(make_float2(w00, w10));
    __hip_bfloat162 hi = __float22bfloat162_rn(make_float2(w01, w11));
    *(__hip_bfloat162*)&Wt[cg * INSIZE + rg] = lo;
    *(__hip_bfloat162*)&Wt[(cg + 1) * INSIZE + rg] = hi;
}

// ---------------------------------------------------------------------------
// out = x @ W + bias : bf16 MFMA, 64x128 block tile, BK=32, 512 blocks (2/CU).
// Same validated swizzles/fragment layouts as R2/R3; A tile is 64 rows now.
//   A: m=lane&15, k=(lane>>4)*8+j ; B: n=lane&15, k=(lane>>4)*8+j
//   C/D: col=lane&15, row=(lane>>4)*4+reg
typedef __attribute__((ext_vector_type(8))) short short8;
typedef __attribute__((ext_vector_type(4))) float float4v;

__global__ __launch_bounds__(256) void k_gemm(const float* __restrict__ X,
                                              const float* __restrict__ ws,
                                              const float* __restrict__ bias,
                                              float* __restrict__ out) {
    __shared__ float As[64 * 32];               // 8 KB, chunk-swizzled
    __shared__ unsigned short Bs[128 * 32];     // 8 KB, chunk-swizzled
    const unsigned short* Wt = (const unsigned short*)(ws + OFF_WT);

    // L = outer*32 + bn*8 + inner : all 4 n-tiles of an m-panel share L%8
    // (same XCD under round-robin dispatch) so X is HBM-fetched once.
    int L = blockIdx.x;              // 0..511
    int inner = L & 7;
    int bn = (L >> 3) & 3;
    int bm = (L >> 5) * 8 + inner;   // 0..127
    int row0 = bm * 64, col0 = bn * 128;

    int t = threadIdx.x;
    int l = t & 63, w = t >> 6;
    int wm = (w & 1) * 32, wn = (w >> 1) * 64;

    float4v acc[2][4] = {};
    int quad = l >> 4;
    int lan = l & 15;

    for (int k0 = 0; k0 < INSIZE; k0 += 32) {
        __syncthreads();
        // A: 64 rows x 32 k fp32; physical chunk P: prow=P>>3, lc=(P&7)^(prow&7)
#pragma unroll
        for (int i = 0; i < 2; ++i) {
            int P = i * 256 + t;
            int prow = P >> 3, pc = P & 7;
            int lc = pc ^ (prow & 7);
            const float* g = X + (size_t)(row0 + prow) * INSIZE + k0 + lc * 4;
            __builtin_amdgcn_global_load_lds(
                (const __attribute__((address_space(1))) void*)g,
                (__attribute__((address_space(3))) void*)(As + P * 4), 16, 0, 0);
        }
        // B: 128 n-rows x 32 k bf16 from Wt
#pragma unroll
        for (int i = 0; i < 2; ++i) {
            int P = i * 256 + t;
            int prow = P >> 2, pc = P & 3;
            int lc = pc ^ ((prow >> 1) & 3);
            const unsigned short* g = Wt + (size_t)(col0 + prow) * INSIZE + k0 + lc * 8;
            __builtin_amdgcn_global_load_lds(
                (const __attribute__((address_space(1))) void*)g,
                (__attribute__((address_space(3))) void*)(Bs + P * 8), 16, 0, 0);
        }
        __syncthreads();

        short8 af[2];
        short8 bf[4];
#pragma unroll
        for (int mi = 0; mi < 2; ++mi) {
            int rl = wm + mi * 16 + lan;
            int c0q = quad * 2;
            const float4v lo = *(const float4v*)(As + (rl * 8 + (c0q ^ (rl & 7))) * 4);
            const float4v hi = *(const float4v*)(As + (rl * 8 + ((c0q + 1) ^ (rl & 7))) * 4);
            union { short8 s; __hip_bfloat162 h[4]; } u;
            u.h[0] = __float22bfloat162_rn(make_float2(lo[0], lo[1]));
            u.h[1] = __float22bfloat162_rn(make_float2(lo[2], lo[3]));
            u.h[2] = __float22bfloat162_rn(make_float2(hi[0], hi[1]));
            u.h[3] = __float22bfloat162_rn(make_float2(hi[2], hi[3]));
            af[mi] = u.s;
        }
#pragma unroll
        for (int ni = 0; ni < 4; ++ni) {
            int rn = wn + ni * 16 + lan;
            int c = quad ^ ((rn >> 1) & 3);
            bf[ni] = *(const short8*)(Bs + (rn * 4 + c) * 8);
        }
#pragma unroll
        for (int mi = 0; mi < 2; ++mi)
#pragma unroll
            for (int ni = 0; ni < 4; ++ni)
                acc[mi][ni] = __builtin_amdgcn_mfma_f32_16x16x32_bf16(
                    af[mi], bf[ni], acc[mi][ni], 0, 0, 0);
    }

#pragma unroll
    for (int ni = 0; ni < 4; ++ni) {
        int c = col0 + wn + ni * 16 + lan;
        float bv = bias[c];
#pragma unroll
        for (int mi = 0; mi < 2; ++mi) {
            int rbase = row0 + wm + mi * 16 + quad * 4;
#pragma unroll
            for (int r = 0; r < 4; ++r)
                out[(size_t)(rbase + r) * INSIZE + c] = acc[mi][ni][r] + bv;
        }
    }
}

// ---------------------------------------------------------------------------
extern "C" void kernel_launch(void* const* d_in, const int* in_sizes, int n_in,
                              void* d_out, int out_size, void* d_ws, size_t ws_size,
                              hipStream_t stream) {
    const float* x    = (const float*)d_in[0];
    const float* p    = (const float*)d_in[1];
    const float* U    = (const float*)d_in[2];
    const float* V    = (const float*)d_in[3];
    const float* bias = (const float*)d_in[4];
    float* ws  = (float*)d_ws;
    float* out = (float*)d_out;

    k_prep<<<193, 256, 0, stream>>>(U, V, p, ws);
    k_AR<<<2, 512, 0, stream>>>(U, V, ws);
    k_WtE<<<256, 256, 0, stream>>>(U, V, ws);
    k_gemm<<<512, 256, 0, stream>>>(x, ws, bias, out);
}